// Round 7
// baseline (1397.762 us; speedup 1.0000x reference)
//
#include <hip/hip_runtime.h>
#include <hip/hip_bf16.h>

// MoE forward, B=4096 E=8 D=1024 H=4096 O=1024, fp32 in/out, bf16 MFMA compute.
//
// out = sum_e p[b,e] * (relu(x @ W1[e] + b1[e]) @ W2[e] + b2[e])
//     = (h' @ W2flat) + sum_e p[b,e]*b2[e]      with h'[b, e*H+h] = p[b,e]*relu(...)
//
// GEMMs: 256x256 tile, BK=64, 512 threads (8 waves 2Mx4N), 128KB LDS dbuf,
// 3-bit row-XOR swizzle (conflict-free, r6-verified: SQ_LDS_BANK_CONFLICT=0),
// register-subtile SOFTWARE PIPELINING (reads issued one phase ahead, quadrant
// order q00,q01,q10,q11), 3 barriers/K-tile, counted vmcnt(4), setprio on MFMA.

#define B_DIM 4096
#define E_DIM 8
#define D_DIM 1024
#define H_DIM 4096
#define O_DIM 1024
#define KTOT  (E_DIM * H_DIM)   // 32768
#define KSPLIT 4

typedef __attribute__((ext_vector_type(8))) short bf16x8;
typedef __attribute__((ext_vector_type(4))) float f32x4;

#define SCHED0 __builtin_amdgcn_sched_barrier(0)

__device__ __forceinline__ unsigned short f2bf(float f) {
  union { float f; unsigned u; } c; c.f = f;
  unsigned r = c.u + 0x7fffu + ((c.u >> 16) & 1u);  // RNE
  return (unsigned short)(r >> 16);
}

__device__ __forceinline__ void gload_lds16(const void* g, void* l) {
  __builtin_amdgcn_global_load_lds(
      (const __attribute__((address_space(1))) void*)g,
      (__attribute__((address_space(3))) void*)l, 16, 0, 0);
}

__device__ __forceinline__ void barfence() {
  asm volatile("" ::: "memory");
  __builtin_amdgcn_s_barrier();
  asm volatile("" ::: "memory");
}

// 3-bit row-XOR swizzle: XOR 16B-slot bits (4-6) with row bits 0-2 (addr bits 7-9).
// Involution; conflict-free b128 (r6: bank-conflict counter == 0).
__device__ __forceinline__ unsigned swzA(unsigned o) {
  return o ^ (((o >> 7) & 7u) << 4);
}

// Stage one 128x64 bf16 half-tile (16KB) into LDS segment `seg`.
__device__ __forceinline__ void stageHalf(const char* gbase, size_t rowBytes, int kByte,
                                          char* seg, int tid) {
  #pragma unroll
  for (int r = 0; r < 2; ++r) {
    unsigned o = (unsigned)((r * 512 + tid) * 16);
    unsigned q = swzA(o);
    gload_lds16(gbase + (size_t)(q >> 7) * rowBytes + kByte + (q & 127), seg + o);
  }
}

__device__ __forceinline__ bf16x8 ldsA(const char* aSeg, int m, int kk, int lane) {
  unsigned o = (unsigned)((m * 16 + (lane & 15)) * 128 + kk * 64 + ((lane >> 4) * 16));
  return *(const bf16x8*)(aSeg + swzA(o));
}
__device__ __forceinline__ bf16x8 ldsB(const char* bSeg, int wn, int n, int kk, int lane) {
  unsigned o = (unsigned)(((wn & 1) * 64 + n * 16 + (lane & 15)) * 128 + kk * 64 + ((lane >> 4) * 16));
  return *(const bf16x8*)(bSeg + swzA(o));
}

// ---- one K-tile, 4 phases, register-pipelined one phase ahead ----
// entry state: aLo,bLo hold THIS tile's fragments (loaded during prev tile P3/P4).
template<bool STAGE, bool PIPE, int VMN>
__device__ __forceinline__ void tileK(
    char* smem, int cur,
    const char* AbC, const char* BbC, size_t rb, int kStage,
    int wm, int wn, int lane, int tid,
    bf16x8 (&aLo)[4][2], bf16x8 (&aHi)[4][2],
    bf16x8 (&bLo)[2][2], bf16x8 (&bHi)[2][2],
    f32x4 (&acc)[8][4])
{
  char* bufC = smem + cur * 65536;
  char* bufN = smem + (cur ^ 1) * 65536;
  const char* aSegC = bufC + wm * 16384;
  const char* bSegC = bufC + (2 + (wn >> 1)) * 16384;
  const char* aSegN = bufN + wm * 16384;
  const char* bSegN = bufN + (2 + (wn >> 1)) * 16384;

  // ---------- P1: issue bHi(cur); MFMA q00 = aLo x bLo ----------
  #pragma unroll
  for (int n = 0; n < 2; ++n)
    #pragma unroll
    for (int kk = 0; kk < 2; ++kk)
      bHi[n][kk] = ldsB(bSegC, wn, 2 + n, kk, lane);
  SCHED0;
  __builtin_amdgcn_s_setprio(1);
  #pragma unroll
  for (int kk = 0; kk < 2; ++kk)
    #pragma unroll
    for (int m = 0; m < 4; ++m)
      #pragma unroll
      for (int n = 0; n < 2; ++n)
        acc[m][n] = __builtin_amdgcn_mfma_f32_16x16x32_bf16(aLo[m][kk], bLo[n][kk], acc[m][n], 0, 0, 0);
  __builtin_amdgcn_s_setprio(0);
  SCHED0;

  // ---------- P2: issue aHi(cur); MFMA q01 = aLo x bHi ----------
  #pragma unroll
  for (int m = 0; m < 4; ++m)
    #pragma unroll
    for (int kk = 0; kk < 2; ++kk)
      aHi[m][kk] = ldsA(aSegC, 4 + m, kk, lane);
  SCHED0;
  __builtin_amdgcn_s_setprio(1);
  #pragma unroll
  for (int kk = 0; kk < 2; ++kk)
    #pragma unroll
    for (int m = 0; m < 4; ++m)
      #pragma unroll
      for (int n = 0; n < 2; ++n)
        acc[m][2 + n] = __builtin_amdgcn_mfma_f32_16x16x32_bf16(aLo[m][kk], bHi[n][kk], acc[m][2 + n], 0, 0, 0);
  __builtin_amdgcn_s_setprio(0);
  SCHED0;
  barfence();   // end-P2: all waves' buf-cur B reads drained (via q00/q01 auto-waits)

  // ---------- P3: stage B(t+2)->cur; vmcnt certify buf-next; issue aLo(t+1); q10 ----------
  if (STAGE) {
    stageHalf(BbC,                     rb, kStage, bufC + 2 * 16384, tid);
    stageHalf(BbC + (size_t)128 * rb,  rb, kStage, bufC + 3 * 16384, tid);
  }
  SCHED0;
  if (VMN >= 0) {
    if (VMN == 4) asm volatile("s_waitcnt vmcnt(4)" ::: "memory");
    else          asm volatile("s_waitcnt vmcnt(0)" ::: "memory");
    barfence();   // buf-next fully landed for ALL waves
  }
  SCHED0;
  if (PIPE) {
    #pragma unroll
    for (int m = 0; m < 4; ++m)
      #pragma unroll
      for (int kk = 0; kk < 2; ++kk)
        aLo[m][kk] = ldsA(aSegN, m, kk, lane);
  }
  SCHED0;
  __builtin_amdgcn_s_setprio(1);
  #pragma unroll
  for (int kk = 0; kk < 2; ++kk)
    #pragma unroll
    for (int m = 0; m < 4; ++m)
      #pragma unroll
      for (int n = 0; n < 2; ++n)
        acc[4 + m][n] = __builtin_amdgcn_mfma_f32_16x16x32_bf16(aHi[m][kk], bLo[n][kk], acc[4 + m][n], 0, 0, 0);
  __builtin_amdgcn_s_setprio(0);
  SCHED0;
  barfence();   // end-P3: all waves' buf-cur A reads drained (q10 auto-wait)

  // ---------- P4: issue bLo(t+1); stage A(t+2)->cur; q11 ----------
  SCHED0;
  if (PIPE) {
    #pragma unroll
    for (int n = 0; n < 2; ++n)
      #pragma unroll
      for (int kk = 0; kk < 2; ++kk)
        bLo[n][kk] = ldsB(bSegN, wn, n, kk, lane);
  }
  if (STAGE) {
    stageHalf(AbC,                     rb, kStage, bufC + 0,     tid);
    stageHalf(AbC + (size_t)128 * rb,  rb, kStage, bufC + 16384, tid);
  }
  SCHED0;
  __builtin_amdgcn_s_setprio(1);
  #pragma unroll
  for (int kk = 0; kk < 2; ++kk)
    #pragma unroll
    for (int m = 0; m < 4; ++m)
      #pragma unroll
      for (int n = 0; n < 2; ++n)
        acc[4 + m][2 + n] = __builtin_amdgcn_mfma_f32_16x16x32_bf16(aHi[m][kk], bHi[n][kk], acc[4 + m][2 + n], 0, 0, 0);
  __builtin_amdgcn_s_setprio(0);
  SCHED0;
}

// ---------------- 256x256 pipelined GEMM  C = A[M,K] * Bt[N,K]^T ----------------
// MODE 1: Cout = bf16( relu(acc + b1[col]) * probs[row, col>>12] ), N=32768
// MODE 2: fp32 partial write to Cout + blockIdx.y*M*N (split-K), N=1024
template<int MODE>
__global__ __launch_bounds__(512, 2)
void gemm8p(const unsigned short* __restrict__ A,
            const unsigned short* __restrict__ Bt,
            void* __restrict__ Cout,
            const float* __restrict__ probs,
            const float* __restrict__ bias,
            int M, int N, int K, int kChunk)
{
  __shared__ __align__(16) char smem[131072];  // 2 buf x (A0,A1,B0,B1) x 16KB

  const int tid = threadIdx.x;
  const int wave = tid >> 6, lane = tid & 63;
  const int wm = wave >> 2, wn = wave & 3;

  int mt, nt, kBeg;
  if (MODE == 1) {
    // 2048 blocks; xcd = bid&7; per-XCD 4x4 (mt,nt) groups for L2 locality
    int bid = blockIdx.x;
    int xcd = bid & 7, seq = bid >> 3;
    int grp = seq >> 4, g = seq & 15;
    mt = (grp & 3) * 4 + (g & 3);
    nt = xcd * 16 + (grp >> 2) * 4 + (g >> 2);
    kBeg = 0;
  } else {
    int x = blockIdx.x;
    mt = (x & 7) * 2 + ((x >> 3) & 1);
    nt = x >> 4;
    kBeg = blockIdx.y * kChunk;
  }

  const char* AbC = (const char*)(A + (size_t)mt * 256 * K);
  const char* BbC = (const char*)(Bt + (size_t)nt * 256 * K);
  const size_t rb = (size_t)K * 2;

  f32x4 acc[8][4] = {};
  bf16x8 aLo[4][2], aHi[4][2], bLo[2][2], bHi[2][2];

  const int NT = kChunk / 64;   // >= 3

  // prologue: stage tile0 -> buf0, tile1 -> buf1
  {
    int k0 = kBeg * 2, k1 = (kBeg + 64) * 2;
    stageHalf(BbC,                    rb, k0, smem + 2 * 16384, tid);
    stageHalf(BbC + (size_t)128 * rb, rb, k0, smem + 3 * 16384, tid);
    stageHalf(AbC,                    rb, k0, smem + 0,         tid);
    stageHalf(AbC + (size_t)128 * rb, rb, k0, smem + 16384,     tid);
    stageHalf(BbC,                    rb, k1, smem + 65536 + 2 * 16384, tid);
    stageHalf(BbC + (size_t)128 * rb, rb, k1, smem + 65536 + 3 * 16384, tid);
    stageHalf(AbC,                    rb, k1, smem + 65536 + 0,         tid);
    stageHalf(AbC + (size_t)128 * rb, rb, k1, smem + 65536 + 16384,     tid);
  }
  asm volatile("s_waitcnt vmcnt(8)" ::: "memory");  // tile0 landed
  barfence();
  SCHED0;
  // preload tile0 aLo,bLo
  #pragma unroll
  for (int m = 0; m < 4; ++m)
    #pragma unroll
    for (int kk = 0; kk < 2; ++kk)
      aLo[m][kk] = ldsA(smem + wm * 16384, m, kk, lane);
  #pragma unroll
  for (int n = 0; n < 2; ++n)
    #pragma unroll
    for (int kk = 0; kk < 2; ++kk)
      bLo[n][kk] = ldsB(smem + (2 + (wn >> 1)) * 16384, wn, n, kk, lane);
  SCHED0;

  for (int t = 0; t < NT - 2; ++t)
    tileK<true, true, 4>(smem, t & 1, AbC, BbC, rb, (kBeg + (t + 2) * 64) * 2,
                         wm, wn, lane, tid, aLo, aHi, bLo, bHi, acc);
  tileK<false, true, 0>(smem, (NT - 2) & 1, AbC, BbC, rb, 0,
                        wm, wn, lane, tid, aLo, aHi, bLo, bHi, acc);
  tileK<false, false, -1>(smem, (NT - 1) & 1, AbC, BbC, rb, 0,
                          wm, wn, lane, tid, aLo, aHi, bLo, bHi, acc);

  // epilogue: C/D layout col = lane&15, row = (lane>>4)*4 + j  [m89-verified]
  const int colBase = nt * 256 + wn * 64;
  const int rowBase = mt * 256 + wm * 128;
  #pragma unroll
  for (int m = 0; m < 8; ++m) {
    #pragma unroll
    for (int n = 0; n < 4; ++n) {
      const int col = colBase + n * 16 + (lane & 15);
      #pragma unroll
      for (int j = 0; j < 4; ++j) {
        const int row = rowBase + m * 16 + ((lane >> 4) * 4) + j;
        float v = acc[m][n][j];
        if (MODE == 1) {
          v += bias[col];
          v = fmaxf(v, 0.0f) * probs[row * E_DIM + (col >> 12)];
          ((unsigned short*)Cout)[(size_t)row * N + col] = f2bf(v);
        } else {
          float* dst = (float*)Cout + (size_t)blockIdx.y * M * N;
          dst[(size_t)row * N + col] = v;
        }
      }
    }
  }
}

// ---------------- gating: probs[b,e] = softmax(x @ Wg + bg) ----------------
__global__ __launch_bounds__(256) void gating_kernel(
    const float* __restrict__ x, const float* __restrict__ Wg,
    const float* __restrict__ bg, float* __restrict__ probs)
{
  __shared__ float sWg[D_DIM * E_DIM];  // 32 KB
  for (int i = threadIdx.x; i < D_DIM * E_DIM; i += 256) sWg[i] = Wg[i];
  __syncthreads();

  const int wave = threadIdx.x >> 6, lane = threadIdx.x & 63;
  const int b = blockIdx.x * 4 + wave;

  float acc[E_DIM] = {};
  const float* xr = x + (size_t)b * D_DIM;
  #pragma unroll
  for (int i = 0; i < D_DIM / 64; ++i) {
    int d = i * 64 + lane;
    float xv = xr[d];
    #pragma unroll
    for (int e = 0; e < E_DIM; ++e) acc[e] += xv * sWg[d * E_DIM + e];
  }
  #pragma unroll
  for (int e = 0; e < E_DIM; ++e) {
    #pragma unroll
    for (int off = 32; off > 0; off >>= 1) acc[e] += __shfl_down(acc[e], off);
  }
  if (lane == 0) {
    float m = -1e30f;
    #pragma unroll
    for (int e = 0; e < E_DIM; ++e) { acc[e] += bg[e]; m = fmaxf(m, acc[e]); }
    float p[E_DIM]; float s = 0.f;
    #pragma unroll
    for (int e = 0; e < E_DIM; ++e) { p[e] = expf(acc[e] - m); s += p[e]; }
    float inv = 1.0f / s;
    #pragma unroll
    for (int e = 0; e < E_DIM; ++e) probs[(size_t)b * E_DIM + e] = p[e] * inv;
  }
}

// ---------------- x (fp32) -> xb (bf16), same layout ----------------
__global__ __launch_bounds__(256) void convert_x_kernel(
    const float* __restrict__ x, unsigned short* __restrict__ xb)
{
  int i = blockIdx.x * 256 + threadIdx.x;  // one float4 per thread
  const float4* src = (const float4*)x;
  float4 v = src[i];
  union { unsigned short u[4]; unsigned long long q; } o;
  o.u[0] = f2bf(v.x); o.u[1] = f2bf(v.y); o.u[2] = f2bf(v.z); o.u[3] = f2bf(v.w);
  *(unsigned long long*)(xb + (size_t)i * 4) = o.q;
}

// ---------------- generic 64x64 transpose+convert ----------------
// dst[eDst + y*ldDst + x] = bf16(src[eSrc + x*ldSrc + y]); full-wave 256B reads.
__global__ __launch_bounds__(256) void transpose_cvt(
    const float* __restrict__ src, unsigned short* __restrict__ dst,
    int ldSrc, int ldDst, size_t srcPlane, size_t dstPlane)
{
  __shared__ float t[64][65];
  const int e = blockIdx.z;
  const int x0 = blockIdx.x * 64;
  const int y0 = blockIdx.y * 64;
  const float* s = src + (size_t)e * srcPlane;
  unsigned short* d = dst + (size_t)e * dstPlane;

  const int c = threadIdx.x & 63;          // along y (contiguous in src)
  const int r4 = threadIdx.x >> 6;         // 4 rows per pass
  #pragma unroll
  for (int i = 0; i < 16; ++i) {
    int r = r4 + 4 * i;
    t[r][c] = s[(size_t)(x0 + r) * ldSrc + y0 + c];
  }
  __syncthreads();

  const int x4 = (threadIdx.x & 15) * 4;   // along x (contiguous in dst)
  const int yb = threadIdx.x >> 4;         // 16 rows per pass
  #pragma unroll
  for (int j = 0; j < 4; ++j) {
    int y = yb + 16 * j;
    union { unsigned short u[4]; unsigned long long q; } o;
    #pragma unroll
    for (int q = 0; q < 4; ++q) o.u[q] = f2bf(t[x4 + q][y]);
    *(unsigned long long*)(d + (size_t)(y0 + y) * ldDst + x0 + x4) = o.q;
  }
}

// ---------------- reduce split-K partials + bias correction ----------------
__global__ __launch_bounds__(256) void reduce_out(
    const float* __restrict__ partial, const float* __restrict__ probs,
    const float* __restrict__ b2, float* __restrict__ out)
{
  const int i = blockIdx.x * 256 + threadIdx.x;        // over B*O/4 float4s
  const int row = i >> 8;                              // O/4 = 256 float4 per row
  const int colv = i & 255;
  const size_t plane = (size_t)B_DIM * O_DIM / 4;

  float4 v = make_float4(0.f, 0.f, 0.f, 0.f);
  #pragma unroll
  for (int ks = 0; ks < KSPLIT; ++ks) {
    float4 p = ((const float4*)partial)[ks * plane + i];
    v.x += p.x; v.y += p.y; v.z += p.z; v.w += p.w;
  }
  #pragma unroll
  for (int e = 0; e < E_DIM; ++e) {
    float pe = probs[row * E_DIM + e];
    float4 b = ((const float4*)b2)[e * (O_DIM / 4) + colv];
    v.x += pe * b.x; v.y += pe * b.y; v.z += pe * b.z; v.w += pe * b.w;
  }
  ((float4*)out)[i] = v;
}

extern "C" void kernel_launch(void* const* d_in, const int* in_sizes, int n_in,
                              void* d_out, int out_size, void* d_ws, size_t ws_size,
                              hipStream_t stream)
{
  const float* x  = (const float*)d_in[0];
  const float* W1 = (const float*)d_in[1];
  const float* b1 = (const float*)d_in[2];
  const float* W2 = (const float*)d_in[3];
  const float* b2 = (const float*)d_in[4];
  const float* Wg = (const float*)d_in[5];
  const float* bg = (const float*)d_in[6];
  float* out = (float*)d_out;

  // workspace layout
  char* ws = (char*)d_ws;
  float*          probs = (float*)ws;                                   // 128 KB
  unsigned short* xb    = (unsigned short*)(ws + (1u << 17));           // 8 MB
  unsigned short* W1t   = (unsigned short*)(ws + (1u << 17) + (8u << 20));       // 64 MB
  unsigned short* W2t   = (unsigned short*)(ws + (1u << 17) + (8u << 20) + (64u << 20)); // 64 MB
  unsigned short* hp    = (unsigned short*)(ws + (1u << 17) + (8u << 20) + (128u << 20)); // 256 MB
  float* partial = (float*)W1t;  // split-K partials alias W1t (dead after GEMM1)

  gating_kernel<<<B_DIM / 4, 256, 0, stream>>>(x, Wg, bg, probs);
  convert_x_kernel<<<(B_DIM * D_DIM / 4) / 256, 256, 0, stream>>>(x, xb);
  // W1 [E][D][H] -> W1t [(e*H+h)][D]: x=d (nX=D), y=h (nY=H)
  transpose_cvt<<<dim3(D_DIM / 64, H_DIM / 64, E_DIM), 256, 0, stream>>>(
      W1, W1t, H_DIM, D_DIM, (size_t)D_DIM * H_DIM, (size_t)H_DIM * D_DIM);
  // W2 [E][H][O] -> W2t [O][e*H+h]: x=h (nX=H), y=o (nY=O)
  transpose_cvt<<<dim3(H_DIM / 64, O_DIM / 64, E_DIM), 256, 0, stream>>>(
      W2, W2t, O_DIM, KTOT, (size_t)H_DIM * O_DIM, (size_t)H_DIM);

  // GEMM1: h' = bf16(p * relu(x @ W1 + b1))   M=4096 N=32768 K=1024
  gemm8p<1><<<dim3((B_DIM / 256) * (KTOT / 256), 1), 512, 0, stream>>>(
      xb, W1t, hp, probs, b1, B_DIM, KTOT, D_DIM, D_DIM);

  // GEMM2: partial[ks] = h' @ W2 (chunk ks)    M=4096 N=1024 K=32768, split-K=4
  gemm8p<2><<<dim3((B_DIM / 256) * (O_DIM / 256), KSPLIT), 512, 0, stream>>>(
      hp, W2t, partial, probs, nullptr, B_DIM, O_DIM, KTOT, KTOT / KSPLIT);

  // reduce partials + sum_e p*b2 -> out
  reduce_out<<<(B_DIM * O_DIM / 4) / 256, 256, 0, stream>>>(partial, probs, b2, out);
}

// Round 8
// 962.526 us; speedup vs baseline: 1.4522x; 1.4522x over previous
//
#include <hip/hip_runtime.h>
#include <hip/hip_bf16.h>

// MoE forward, B=4096 E=8 D=1024 H=4096 O=1024, fp32 in/out, bf16 MFMA compute.
//
// out = sum_e p[b,e] * (relu(x @ W1[e] + b1[e]) @ W2[e] + b2[e])
//     = (h' @ W2flat) + sum_e p[b,e]*b2[e]      with h'[b, e*H+h] = p[b,e]*relu(...)
//
// GEMM main loop = round-6 proven structure (358us, SQ_LDS_BANK_CONFLICT=0):
// 256x256 tile, BK=64, 512 thr (8 waves 2Mx4N), 128KB LDS dbuf, 3-bit row-XOR
// swizzle both-sides, per-phase lgkmcnt(0)-before-MFMA, counted vmcnt(8),
// setprio on MFMA. Round-7's sched_barrier pipelining REVERTED (m141 regression).
// New in r8: MODE1 epilogue repacks C through LDS for 16B coalesced stores;
// vectorized float4 transpose kernels.

#define B_DIM 4096
#define E_DIM 8
#define D_DIM 1024
#define H_DIM 4096
#define O_DIM 1024
#define KTOT  (E_DIM * H_DIM)   // 32768
#define KSPLIT 4

typedef __attribute__((ext_vector_type(8))) short bf16x8;
typedef __attribute__((ext_vector_type(4))) float f32x4;

__device__ __forceinline__ unsigned short f2bf(float f) {
  union { float f; unsigned u; } c; c.f = f;
  unsigned r = c.u + 0x7fffu + ((c.u >> 16) & 1u);  // RNE
  return (unsigned short)(r >> 16);
}

__device__ __forceinline__ void gload_lds16(const void* g, void* l) {
  __builtin_amdgcn_global_load_lds(
      (const __attribute__((address_space(1))) void*)g,
      (__attribute__((address_space(3))) void*)l, 16, 0, 0);
}

__device__ __forceinline__ void barfence() {
  asm volatile("" ::: "memory");
  __builtin_amdgcn_s_barrier();
  asm volatile("" ::: "memory");
}

// 3-bit row-XOR swizzle: XOR 16B-slot bits (4-6) with row bits 0-2 (addr bits 7-9).
// Involution; conflict-free b128 (r6: bank-conflict counter == 0).
__device__ __forceinline__ unsigned swzA(unsigned o) {
  return o ^ (((o >> 7) & 7u) << 4);
}

// Stage one 128x64 bf16 half-tile (16KB) into LDS segment `seg`.
// LDS dest linear (wave-uniform base + lane*16); global source pre-inverse-swizzled.
__device__ __forceinline__ void stageHalf(const char* gbase, size_t rowBytes, int kByte,
                                          char* seg, int tid) {
  #pragma unroll
  for (int r = 0; r < 2; ++r) {
    unsigned o = (unsigned)((r * 512 + tid) * 16);
    unsigned q = swzA(o);
    gload_lds16(gbase + (size_t)(q >> 7) * rowBytes + kByte + (q & 127), seg + o);
  }
}

// ---- one K-tile (BK=64) = 4 phases; quadrant order (0,0),(0,1),(1,1),(1,0) ----
template<bool STAGE, int VMN>
__device__ __forceinline__ void tile4(
    char* smem, int bufOff,
    const char* AbC, const char* BbC, size_t rbA, size_t rbB, int kStage,
    int wm, int wn, int lane, int tid, f32x4 (&acc)[8][4])
{
  bf16x8 aF[4][2], bLo[2][2], bHi[2][2];
  const char* aSeg = smem + bufOff + wm * 16384;            // A-half = wm
  const char* bSeg = smem + bufOff + (2 + (wn >> 1)) * 16384; // B-half = wn>>1

  // ---------- P1: quadrant (0,0) ----------
  #pragma unroll
  for (int m = 0; m < 4; ++m)
    #pragma unroll
    for (int kk = 0; kk < 2; ++kk) {
      unsigned o = (unsigned)((m * 16 + (lane & 15)) * 128 + kk * 64 + ((lane >> 4) * 16));
      aF[m][kk] = *(const bf16x8*)(aSeg + swzA(o));
    }
  #pragma unroll
  for (int n = 0; n < 2; ++n)
    #pragma unroll
    for (int kk = 0; kk < 2; ++kk) {
      unsigned o = (unsigned)(((wn & 1) * 64 + n * 16 + (lane & 15)) * 128 + kk * 64 + ((lane >> 4) * 16));
      bLo[n][kk] = *(const bf16x8*)(bSeg + swzA(o));
    }
  asm volatile("s_waitcnt lgkmcnt(8)" ::: "memory");
  barfence();
  asm volatile("s_waitcnt lgkmcnt(0)" ::: "memory");
  __builtin_amdgcn_s_setprio(1);
  #pragma unroll
  for (int m = 0; m < 4; ++m)
    #pragma unroll
    for (int n = 0; n < 2; ++n)
      #pragma unroll
      for (int kk = 0; kk < 2; ++kk)
        acc[m][n] = __builtin_amdgcn_mfma_f32_16x16x32_bf16(aF[m][kk], bLo[n][kk], acc[m][n], 0, 0, 0);
  __builtin_amdgcn_s_setprio(0);
  barfence();

  // ---------- P2: quadrant (0,1) ----------
  #pragma unroll
  for (int n = 0; n < 2; ++n)
    #pragma unroll
    for (int kk = 0; kk < 2; ++kk) {
      unsigned o = (unsigned)(((wn & 1) * 64 + (2 + n) * 16 + (lane & 15)) * 128 + kk * 64 + ((lane >> 4) * 16));
      bHi[n][kk] = *(const bf16x8*)(bSeg + swzA(o));
    }
  barfence();
  asm volatile("s_waitcnt lgkmcnt(0)" ::: "memory");
  __builtin_amdgcn_s_setprio(1);
  #pragma unroll
  for (int m = 0; m < 4; ++m)
    #pragma unroll
    for (int n = 0; n < 2; ++n)
      #pragma unroll
      for (int kk = 0; kk < 2; ++kk)
        acc[m][2 + n] = __builtin_amdgcn_mfma_f32_16x16x32_bf16(aF[m][kk], bHi[n][kk], acc[m][2 + n], 0, 0, 0);
  __builtin_amdgcn_s_setprio(0);
  barfence();

  // ---------- P3: quadrant (1,1); stage next-tile B halves ----------
  #pragma unroll
  for (int m = 0; m < 4; ++m)
    #pragma unroll
    for (int kk = 0; kk < 2; ++kk) {
      unsigned o = (unsigned)(((4 + m) * 16 + (lane & 15)) * 128 + kk * 64 + ((lane >> 4) * 16));
      aF[m][kk] = *(const bf16x8*)(aSeg + swzA(o));
    }
  if (STAGE) {
    stageHalf(BbC,                     rbB, kStage, smem + bufOff + 2 * 16384, tid);
    stageHalf(BbC + (size_t)128 * rbB, rbB, kStage, smem + bufOff + 3 * 16384, tid);
  }
  barfence();
  asm volatile("s_waitcnt lgkmcnt(0)" ::: "memory");
  __builtin_amdgcn_s_setprio(1);
  #pragma unroll
  for (int m = 0; m < 4; ++m)
    #pragma unroll
    for (int n = 0; n < 2; ++n)
      #pragma unroll
      for (int kk = 0; kk < 2; ++kk)
        acc[4 + m][2 + n] = __builtin_amdgcn_mfma_f32_16x16x32_bf16(aF[m][kk], bHi[n][kk], acc[4 + m][2 + n], 0, 0, 0);
  __builtin_amdgcn_s_setprio(0);
  barfence();

  // ---------- P4: quadrant (1,0); stage next-tile A halves; counted vmcnt ----------
  if (STAGE) {
    stageHalf(AbC,                     rbA, kStage, smem + bufOff + 0,     tid);
    stageHalf(AbC + (size_t)128 * rbA, rbA, kStage, smem + bufOff + 16384, tid);
  }
  if (VMN == 8)      asm volatile("s_waitcnt vmcnt(8)" ::: "memory");
  else if (VMN == 0) asm volatile("s_waitcnt vmcnt(0)" ::: "memory");
  barfence();
  __builtin_amdgcn_s_setprio(1);
  #pragma unroll
  for (int m = 0; m < 4; ++m)
    #pragma unroll
    for (int n = 0; n < 2; ++n)
      #pragma unroll
      for (int kk = 0; kk < 2; ++kk)
        acc[4 + m][n] = __builtin_amdgcn_mfma_f32_16x16x32_bf16(aF[m][kk], bLo[n][kk], acc[4 + m][n], 0, 0, 0);
  __builtin_amdgcn_s_setprio(0);
  barfence();
}

// ---------------- 256x256 8-phase GEMM  C = A[M,K] * Bt[N,K]^T ----------------
// MODE 1: Cout = bf16( relu(acc + b1[col]) * probs[row, col>>12] ), N=32768
//         (LDS-repacked epilogue: 16B coalesced stores)
// MODE 2: fp32 partial write to Cout + blockIdx.y*M*N (split-K), N=1024
template<int MODE>
__global__ __launch_bounds__(512, 2)
void gemm8p(const unsigned short* __restrict__ A,
            const unsigned short* __restrict__ Bt,
            void* __restrict__ Cout,
            const float* __restrict__ probs,
            const float* __restrict__ bias,
            int M, int N, int K, int kChunk)
{
  __shared__ __align__(16) char smem[131072];  // 2 buf x (A0,A1,B0,B1) x 16KB

  const int tid = threadIdx.x;
  const int wave = tid >> 6, lane = tid & 63;
  const int wm = wave >> 2, wn = wave & 3;

  int mt, nt, kBeg;
  if (MODE == 1) {
    // 2048 blocks; xcd = bid&7 (round-robin dispatch); per-XCD 4x4 (mt,nt) groups
    int bid = blockIdx.x;
    int xcd = bid & 7, seq = bid >> 3;
    int grp = seq >> 4, g = seq & 15;
    mt = (grp & 3) * 4 + (g & 3);
    nt = xcd * 16 + (grp >> 2) * 4 + (g >> 2);
    kBeg = 0;
  } else {
    // 64 x-blocks: the 4 nt-blocks sharing an A panel land on one XCD
    int x = blockIdx.x;
    mt = (x & 7) * 2 + ((x >> 3) & 1);
    nt = x >> 4;
    kBeg = blockIdx.y * kChunk;
  }

  const char* AbC = (const char*)(A + (size_t)mt * 256 * K);
  const char* BbC = (const char*)(Bt + (size_t)nt * 256 * K);
  const size_t rbA = (size_t)K * 2, rbB = (size_t)K * 2;

  f32x4 acc[8][4] = {};

  const int NT = kChunk / 64;   // K-tiles (even, >= 4)
  const int NI = NT / 2;

  // prologue: stage tile0 -> buf0, tile1 -> buf1 (order: B,B,A,A per tile)
  {
    int k0 = kBeg * 2, k1 = (kBeg + 64) * 2;
    stageHalf(BbC,                    rbB, k0, smem + 2 * 16384, tid);
    stageHalf(BbC + (size_t)128 * rbB, rbB, k0, smem + 3 * 16384, tid);
    stageHalf(AbC,                    rbA, k0, smem + 0,         tid);
    stageHalf(AbC + (size_t)128 * rbA, rbA, k0, smem + 16384,    tid);
    stageHalf(BbC,                    rbB, k1, smem + 65536 + 2 * 16384, tid);
    stageHalf(BbC + (size_t)128 * rbB, rbB, k1, smem + 65536 + 3 * 16384, tid);
    stageHalf(AbC,                    rbA, k1, smem + 65536 + 0,         tid);
    stageHalf(AbC + (size_t)128 * rbA, rbA, k1, smem + 65536 + 16384,    tid);
  }
  asm volatile("s_waitcnt vmcnt(8)" ::: "memory");  // tile0 landed
  barfence();

  for (int i = 0; i < NI - 1; ++i) {
    int ks0 = (kBeg + (2 * i + 2) * 64) * 2;
    int ks1 = (kBeg + (2 * i + 3) * 64) * 2;
    tile4<true, 8>(smem, 0,     AbC, BbC, rbA, rbB, ks0, wm, wn, lane, tid, acc);
    tile4<true, 8>(smem, 65536, AbC, BbC, rbA, rbB, ks1, wm, wn, lane, tid, acc);
  }
  // peeled last iteration: no staging; drain remaining loads before buf1 use
  tile4<false, 0>(smem, 0,     AbC, BbC, rbA, rbB, 0, wm, wn, lane, tid, acc);
  tile4<false, -1>(smem, 65536, AbC, BbC, rbA, rbB, 0, wm, wn, lane, tid, acc);

  // epilogue: C/D layout col = lane&15, row = (lane>>4)*4 + j  [m89-verified]
  const int colBase = nt * 256 + wn * 64;
  const int rowBase = mt * 256 + wm * 128;

  if (MODE == 1) {
    // Repack wave's 128x64 bf16 sub-tile via private LDS region (free after last
    // barrier; no inter-wave sharing -> no extra sync). Then 16B coalesced stores:
    // 8 lanes x 16B = 128B contiguous per C row.
    char* myseg = smem + wave * 16384;   // 128 rows x 128B
    const int eIdx = colBase >> 12;      // expert id is wave-uniform (4096 % 64 == 0)
    #pragma unroll
    for (int m = 0; m < 8; ++m) {
      #pragma unroll
      for (int n = 0; n < 4; ++n) {
        const int col = colBase + n * 16 + (lane & 15);
        const float bv = bias[col];
        #pragma unroll
        for (int j = 0; j < 4; ++j) {
          const int row = rowBase + m * 16 + ((lane >> 4) * 4) + j;
          float v = acc[m][n][j] + bv;
          v = fmaxf(v, 0.0f) * probs[row * E_DIM + eIdx];
          *(unsigned short*)(myseg + (m * 16 + ((lane >> 4) * 4) + j) * 128 +
                             (n * 16 + (lane & 15)) * 2) = f2bf(v);
        }
      }
    }
    unsigned short* Cw = (unsigned short*)Cout;
    const int lc = (lane & 7) * 8;          // 8 bf16 = 16B per lane
    #pragma unroll
    for (int i = 0; i < 16; ++i) {
      int lr = i * 8 + (lane >> 3);         // 0..127
      bf16x8 vv = *(const bf16x8*)(myseg + lr * 128 + lc * 2);
      *(bf16x8*)(&Cw[(size_t)(rowBase + lr) * N + colBase + lc]) = vv;
    }
  } else {
    float* dst = (float*)Cout + (size_t)blockIdx.y * M * N;
    #pragma unroll
    for (int m = 0; m < 8; ++m) {
      #pragma unroll
      for (int n = 0; n < 4; ++n) {
        const int col = colBase + n * 16 + (lane & 15);
        #pragma unroll
        for (int j = 0; j < 4; ++j) {
          const int row = rowBase + m * 16 + ((lane >> 4) * 4) + j;
          dst[(size_t)row * N + col] = acc[m][n][j];
        }
      }
    }
  }
}

// ---------------- gating: probs[b,e] = softmax(x @ Wg + bg) ----------------
__global__ __launch_bounds__(256) void gating_kernel(
    const float* __restrict__ x, const float* __restrict__ Wg,
    const float* __restrict__ bg, float* __restrict__ probs)
{
  __shared__ float sWg[D_DIM * E_DIM];  // 32 KB
  for (int i = threadIdx.x; i < D_DIM * E_DIM; i += 256) sWg[i] = Wg[i];
  __syncthreads();

  const int wave = threadIdx.x >> 6, lane = threadIdx.x & 63;
  const int b = blockIdx.x * 4 + wave;

  float acc[E_DIM] = {};
  const float* xr = x + (size_t)b * D_DIM;
  #pragma unroll
  for (int i = 0; i < D_DIM / 64; ++i) {
    int d = i * 64 + lane;
    float xv = xr[d];
    #pragma unroll
    for (int e = 0; e < E_DIM; ++e) acc[e] += xv * sWg[d * E_DIM + e];
  }
  #pragma unroll
  for (int e = 0; e < E_DIM; ++e) {
    #pragma unroll
    for (int off = 32; off > 0; off >>= 1) acc[e] += __shfl_down(acc[e], off);
  }
  if (lane == 0) {
    float m = -1e30f;
    #pragma unroll
    for (int e = 0; e < E_DIM; ++e) { acc[e] += bg[e]; m = fmaxf(m, acc[e]); }
    float p[E_DIM]; float s = 0.f;
    #pragma unroll
    for (int e = 0; e < E_DIM; ++e) { p[e] = expf(acc[e] - m); s += p[e]; }
    float inv = 1.0f / s;
    #pragma unroll
    for (int e = 0; e < E_DIM; ++e) probs[(size_t)b * E_DIM + e] = p[e] * inv;
  }
}

// ---------------- x (fp32) -> xb (bf16), same layout ----------------
__global__ __launch_bounds__(256) void convert_x_kernel(
    const float* __restrict__ x, unsigned short* __restrict__ xb)
{
  int i = blockIdx.x * 256 + threadIdx.x;  // one float4 per thread
  const float4* src = (const float4*)x;
  float4 v = src[i];
  union { unsigned short u[4]; unsigned long long q; } o;
  o.u[0] = f2bf(v.x); o.u[1] = f2bf(v.y); o.u[2] = f2bf(v.z); o.u[3] = f2bf(v.w);
  *(unsigned long long*)(xb + (size_t)i * 4) = o.q;
}

// ---------------- generic 64x64 transpose+convert (vectorized) ----------------
// dst[e*dstPlane + y*ldDst + x] = bf16(src[e*srcPlane + x*ldSrc + y])
// reads float4 (256B/quarter-wave segments), writes 8B packed bf16 (128B/row).
__global__ __launch_bounds__(256) void transpose_cvt(
    const float* __restrict__ src, unsigned short* __restrict__ dst,
    int ldSrc, int ldDst, size_t srcPlane, size_t dstPlane)
{
  __shared__ float t[64][65];
  const int e = blockIdx.z;
  const int x0 = blockIdx.x * 64;   // src row block / dst col block
  const int y0 = blockIdx.y * 64;   // src col block / dst row block
  const float* s = src + (size_t)e * srcPlane;
  unsigned short* d = dst + (size_t)e * dstPlane;

  const int rr = threadIdx.x >> 4;          // 0..15
  const int cc = (threadIdx.x & 15) * 4;    // 0..60
  #pragma unroll
  for (int i = 0; i < 4; ++i) {
    int r = rr + 16 * i;
    float4 v = *(const float4*)&s[(size_t)(x0 + r) * ldSrc + y0 + cc];
    t[r][cc] = v.x; t[r][cc + 1] = v.y; t[r][cc + 2] = v.z; t[r][cc + 3] = v.w;
  }
  __syncthreads();

  const int x4 = (threadIdx.x & 15) * 4;    // dst col offset (4 bf16 = 8B)
  const int yb = threadIdx.x >> 4;          // dst row
  #pragma unroll
  for (int j = 0; j < 4; ++j) {
    int y = yb + 16 * j;
    union { unsigned short u[4]; unsigned long long q; } o;
    #pragma unroll
    for (int q = 0; q < 4; ++q) o.u[q] = f2bf(t[x4 + q][y]);
    *(unsigned long long*)(d + (size_t)(y0 + y) * ldDst + x0 + x4) = o.q;
  }
}

// ---------------- reduce split-K partials + bias correction ----------------
__global__ __launch_bounds__(256) void reduce_out(
    const float* __restrict__ partial, const float* __restrict__ probs,
    const float* __restrict__ b2, float* __restrict__ out)
{
  const int i = blockIdx.x * 256 + threadIdx.x;        // over B*O/4 float4s
  const int row = i >> 8;                              // O/4 = 256 float4 per row
  const int colv = i & 255;
  const size_t plane = (size_t)B_DIM * O_DIM / 4;

  float4 v = make_float4(0.f, 0.f, 0.f, 0.f);
  #pragma unroll
  for (int ks = 0; ks < KSPLIT; ++ks) {
    float4 p = ((const float4*)partial)[ks * plane + i];
    v.x += p.x; v.y += p.y; v.z += p.z; v.w += p.w;
  }
  #pragma unroll
  for (int e = 0; e < E_DIM; ++e) {
    float pe = probs[row * E_DIM + e];
    float4 b = ((const float4*)b2)[e * (O_DIM / 4) + colv];
    v.x += pe * b.x; v.y += pe * b.y; v.z += pe * b.z; v.w += pe * b.w;
  }
  ((float4*)out)[i] = v;
}

extern "C" void kernel_launch(void* const* d_in, const int* in_sizes, int n_in,
                              void* d_out, int out_size, void* d_ws, size_t ws_size,
                              hipStream_t stream)
{
  const float* x  = (const float*)d_in[0];
  const float* W1 = (const float*)d_in[1];
  const float* b1 = (const float*)d_in[2];
  const float* W2 = (const float*)d_in[3];
  const float* b2 = (const float*)d_in[4];
  const float* Wg = (const float*)d_in[5];
  const float* bg = (const float*)d_in[6];
  float* out = (float*)d_out;

  // workspace layout
  char* ws = (char*)d_ws;
  float*          probs = (float*)ws;                                   // 128 KB
  unsigned short* xb    = (unsigned short*)(ws + (1u << 17));           // 8 MB
  unsigned short* W1t   = (unsigned short*)(ws + (1u << 17) + (8u << 20));       // 64 MB
  unsigned short* W2t   = (unsigned short*)(ws + (1u << 17) + (8u << 20) + (64u << 20)); // 64 MB
  unsigned short* hp    = (unsigned short*)(ws + (1u << 17) + (8u << 20) + (128u << 20)); // 256 MB
  float* partial = (float*)W1t;  // split-K partials alias W1t (dead after GEMM1)

  gating_kernel<<<B_DIM / 4, 256, 0, stream>>>(x, Wg, bg, probs);
  convert_x_kernel<<<(B_DIM * D_DIM / 4) / 256, 256, 0, stream>>>(x, xb);
  // W1 [E][D][H] -> W1t [(e*H+h)][D]: x=d (nX=D), y=h (nY=H)
  transpose_cvt<<<dim3(D_DIM / 64, H_DIM / 64, E_DIM), 256, 0, stream>>>(
      W1, W1t, H_DIM, D_DIM, (size_t)D_DIM * H_DIM, (size_t)H_DIM * D_DIM);
  // W2 [E][H][O] -> W2t [O][e*H+h]: x=h (nX=H), y=o (nY=O)
  transpose_cvt<<<dim3(H_DIM / 64, O_DIM / 64, E_DIM), 256, 0, stream>>>(
      W2, W2t, O_DIM, KTOT, (size_t)H_DIM * O_DIM, (size_t)H_DIM);

  // GEMM1: h' = bf16(p * relu(x @ W1 + b1))   M=4096 N=32768 K=1024
  gemm8p<1><<<dim3((B_DIM / 256) * (KTOT / 256), 1), 512, 0, stream>>>(
      xb, W1t, hp, probs, b1, B_DIM, KTOT, D_DIM, D_DIM);

  // GEMM2: partial[ks] = h' @ W2 (chunk ks)    M=4096 N=1024 K=32768, split-K=4
  gemm8p<2><<<dim3((B_DIM / 256) * (O_DIM / 256), KSPLIT), 512, 0, stream>>>(
      hp, W2t, partial, probs, nullptr, B_DIM, O_DIM, KTOT, KTOT / KSPLIT);

  // reduce partials + sum_e p*b2 -> out
  reduce_out<<<(B_DIM * O_DIM / 4) / 256, 256, 0, stream>>>(partial, probs, b2, out);
}